// Round 4
// baseline (142.247 us; speedup 1.0000x reference)
//
#include <hip/hip_runtime.h>
#include <hip/hip_bf16.h>

// CrossAttention: B=4, C=256, H=W=64 -> N=M=4096, RC=32
// v11: occupancy + barrier fix for attn.
//  - grid 512 x 512thr: 32 n-rows/block, 2 blocks/CU (4 waves/SIMD, was 2).
//  - QK split 4 ways: wave w<4 handles (q-tile w&1, m-half w>>1): 2 MFMA +
//    8 exp per iter (serial chain halved). l partials via l_sh[2][32].
//  - all 8 waves PV: one 32nx32dx64m scaled MFMA/iter (d-slice wave*32).
//  - __syncthreads() -> s_waitcnt lgkmcnt(0) + raw s_barrier (asm-fenced):
//    V/K global prefetches stay in flight across barriers (no vmcnt drain).

#define B_ 4
#define C_ 256
#define N_ 4096
#define M_ 4096
#define SCALE_ 0.17677669529663687f  // 1/sqrt(32)

typedef __bf16 bf16x8 __attribute__((ext_vector_type(8)));
typedef float f32x4 __attribute__((ext_vector_type(4)));
typedef float f32x16 __attribute__((ext_vector_type(16)));
typedef int i32x8 __attribute__((ext_vector_type(8)));

#define AS1 __attribute__((address_space(1)))
#define AS3 __attribute__((address_space(3)))

static __device__ __forceinline__ unsigned short f2bf(float f) {
    unsigned int u = __float_as_uint(f);
    return (unsigned short)((u + 0x7fffu + ((u >> 16) & 1u)) >> 16);
}
static __device__ __forceinline__ unsigned bfpk(float a, float b) {
    return (unsigned)f2bf(a) | ((unsigned)f2bf(b) << 16);
}
// LDS-ordering barrier that does NOT drain vmcnt: ds ops complete, global
// register loads stay in flight. asm memory clobbers fence compiler motion
// on both sides (no LDS op hoisted above / sunk below the barrier).
static __device__ __forceinline__ void p_barrier() {
    asm volatile("s_waitcnt lgkmcnt(0)" ::: "memory");
    __builtin_amdgcn_s_barrier();
    asm volatile("" ::: "memory");
}

// ---------------------------------------------------------------------------
// prep: weights -> bf16 MFMA fragment order. grid 40 x 256. (unchanged)
// ---------------------------------------------------------------------------
__global__ __launch_bounds__(256) void prep(
        const float* __restrict__ Wq, const float* __restrict__ Wk,
        const float* __restrict__ Wv, uint4* __restrict__ Wqf,
        uint4* __restrict__ Wkf, uint4* __restrict__ Wvf) {
    int bid = blockIdx.x, t = threadIdx.x;
    const float* W;
    uint4* dst;
    int frag;
    if (bid < 32)      { W = Wv; dst = Wvf; frag = (bid * 256 + t) >> 6; }
    else if (bid < 36) { W = Wq; dst = Wqf; frag = ((bid - 32) * 256 + t) >> 6; }
    else               { W = Wk; dst = Wkf; frag = ((bid - 36) * 256 + t) >> 6; }
    int lane = t & 63, low = lane & 15, q = lane >> 4;
    int fch = frag & 7, fr = frag >> 3;
    const float* wp = W + (size_t)(fr * 16 + low) * C_ + fch * 32 + q * 8;
    float4 w0 = *(const float4*)wp;
    float4 w1 = *(const float4*)(wp + 4);
    uint4 pk = {bfpk(w0.x, w0.y), bfpk(w0.z, w0.w),
                bfpk(w1.x, w1.y), bfpk(w1.z, w1.w)};
    dst[(size_t)frag * 64 + lane] = pk;
}

// ---------------------------------------------------------------------------
// Fused transpose + projections. grid 512 x 256. (unchanged from v6)
// ---------------------------------------------------------------------------
__global__ __launch_bounds__(256, 2) void fused_proj(
        const float* __restrict__ x, const float* __restrict__ ctx,
        const uint4* __restrict__ Wqf, const uint4* __restrict__ Wkf,
        const uint4* __restrict__ Wvf,
        const float* __restrict__ bq, const float* __restrict__ bk,
        const float* __restrict__ bv,
        unsigned short* __restrict__ Qf, unsigned short* __restrict__ Kf,
        unsigned char* __restrict__ Vf) {
    __shared__ unsigned short X[64][264];
    __shared__ unsigned short Pl[4][16 * 40];
    __shared__ unsigned char  Vw[4][16 * 40];

    int bid = blockIdx.x;
    bool isX = bid >= 256;
    int lb = bid & 255;
    int b = lb >> 6, pt64 = lb & 63;
    const float* __restrict__ in = (isX ? x : ctx) + (size_t)b * C_ * N_ + pt64 * 64;
    int t = threadIdx.x, wg = t >> 6, lane = t & 63;
    int low = lane & 15, q = lane >> 4;

    {
        int pL = lane;
        const float* s0 = in + pL;
#pragma unroll
        for (int ct = 0; ct < 4; ct++) {
            const float* s2 = s0 + (size_t)(ct * 64 + wg * 16) * N_;
            float v[16];
#pragma unroll
            for (int k = 0; k < 16; k++) v[k] = s2[(size_t)k * N_];
#pragma unroll
            for (int k = 0; k < 16; k += 2)
                *(unsigned*)&X[pL][ct * 64 + wg * 16 + k] = bfpk(v[k], v[k + 1]);
        }
    }
    __syncthreads();

    {
        const uint4* __restrict__ Wf = isX ? Wqf : Wkf;
        const float* __restrict__ bias = isX ? bq : bk;
        unsigned short* __restrict__ dst = isX ? Qf : Kf;
        bf16x8 xf[8];
#pragma unroll
        for (int ch = 0; ch < 8; ch++)
            xf[ch] = *(const bf16x8*)&X[wg * 16 + low][ch * 32 + q * 8];
        const f32x4 zero = {0.f, 0.f, 0.f, 0.f};
        f32x4 acc[2] = {zero, zero};
#pragma unroll
        for (int rt = 0; rt < 2; rt++)
#pragma unroll
            for (int ch = 0; ch < 8; ch++) {
                uint4 wv = Wf[(rt * 8 + ch) * 64 + lane];
                acc[rt] = __builtin_amdgcn_mfma_f32_16x16x32_bf16(
                    __builtin_bit_cast(bf16x8, wv), xf[ch], acc[rt], 0, 0, 0);
            }
        unsigned short* Pw = &Pl[wg][0];
#pragma unroll
        for (int rt = 0; rt < 2; rt++) {
            float b0 = bias[rt * 16 + q * 4 + 0], b1 = bias[rt * 16 + q * 4 + 1];
            float b2 = bias[rt * 16 + q * 4 + 2], b3 = bias[rt * 16 + q * 4 + 3];
            uint2 pk = {bfpk(acc[rt][0] + b0, acc[rt][1] + b1),
                        bfpk(acc[rt][2] + b2, acc[rt][3] + b3)};
            *(uint2*)(Pw + low * 40 + rt * 16 + q * 4) = pk;
        }
        uint4 frag = *(const uint4*)(Pw + low * 40 + q * 8);
        ((uint4*)dst)[((size_t)b * 256 + pt64 * 4 + wg) * 64 + lane] = frag;
    }

    if (!isX) {
        int mstep = wg >> 1, dh = wg & 1;
        bf16x8 vfr[2][8];
#pragma unroll
        for (int mt = 0; mt < 2; mt++)
#pragma unroll
            for (int ch = 0; ch < 8; ch++)
                vfr[mt][ch] = *(const bf16x8*)&X[mstep * 32 + mt * 16 + low][ch * 32 + q * 8];
        unsigned char* Vv = &Vw[wg][0];
        int msg = pt64 * 2 + mstep;
        const f32x4 zero = {0.f, 0.f, 0.f, 0.f};
#pragma unroll
        for (int dt8 = 0; dt8 < 8; dt8++) {
            int dt = dh * 8 + dt8;
            f32x4 a0 = zero, a1 = zero;
#pragma unroll
            for (int ch = 0; ch < 8; ch++) {
                uint4 wv = Wvf[(dt * 8 + ch) * 64 + lane];
                bf16x8 wfr = __builtin_bit_cast(bf16x8, wv);
                a0 = __builtin_amdgcn_mfma_f32_16x16x32_bf16(vfr[0][ch], wfr, a0, 0, 0, 0);
                a1 = __builtin_amdgcn_mfma_f32_16x16x32_bf16(vfr[1][ch], wfr, a1, 0, 0, 0);
            }
            float bb = bv[dt * 16 + low];
            unsigned w0 = __builtin_amdgcn_cvt_pk_fp8_f32(a0[0] + bb, a0[1] + bb, 0, false);
            w0 = __builtin_amdgcn_cvt_pk_fp8_f32(a0[2] + bb, a0[3] + bb, w0, true);
            unsigned w1 = __builtin_amdgcn_cvt_pk_fp8_f32(a1[0] + bb, a1[1] + bb, 0, false);
            w1 = __builtin_amdgcn_cvt_pk_fp8_f32(a1[2] + bb, a1[3] + bb, w1, true);
            *(unsigned*)(Vv + low * 40 + q * 4) = w0;
            *(unsigned*)(Vv + low * 40 + 16 + q * 4) = w1;
            uint2 fr = *(const uint2*)(Vv + low * 40 + q * 8);
            ((uint2*)Vf)[(((size_t)b * 128 + msg) * 16 + dt) * 64 + lane] = fr;
        }
    }
}

// ---------------------------------------------------------------------------
// Flash attention v11. grid 512 x 512 (2 blocks/CU, 8 waves each).
// Block = (b, g): 32 n rows (2 q-tiles), ALL 4096 m.
// Waves 0-3: QK^T + softmax for (q-tile = w&1, m-half = w>>1): 2 MFMA +
// 8 exp per iter. All 8 waves: PV for d-slice [w*32, w*32+32) via one
// mfma_scale_f32_32x32x64_f8f6f4 per iter. P fp8 LDS ping-pong; V frags
// global->VGPR software-pipelined; counted barrier (no vmcnt drain).
// Epilogue: l via l_sh[2][32]; O -> bf16 LDS (stride 129) -> gamma*O/l + x.
// ---------------------------------------------------------------------------
__global__ __launch_bounds__(512, 4) void attn(
        const unsigned short* __restrict__ Qf, const unsigned short* __restrict__ Kf,
        const unsigned char* __restrict__ Vf, const float* __restrict__ x,
        const float* __restrict__ gamma, float* __restrict__ out) {
    __shared__ __align__(16) unsigned char Pb[2][2][16 * 80];  // 5120 B
    __shared__ float l_sh[2][32];
    __shared__ unsigned Ot[32 * 129];                          // 16512 B

    // bijective swizzle: XCD pair {2b,2b+1} hosts all 128 blocks of b ->
    // per-XCD K+V working set 2 MB (L2-resident).
    int bid = blockIdx.x;
    int xcd = bid & 7;
    int b = xcd >> 1;
    int g = ((xcd & 1) << 6) | (bid >> 3);   // 0..127; n0 = g*32

    int wave = threadIdx.x >> 6, lane = threadIdx.x & 63;
    int q = lane >> 4, low = lane & 15;
    int hi = lane >> 5;                      // m-half selector in PV frags
    int dsel = q & 1;                        // n/d tile-parity selector
    int l31 = lane & 31;
    bool isQK = wave < 4;
    int t = wave & 1;                        // QK q-tile (16 rows)
    int h = (wave >> 1) & 1;                 // QK m-half (32 of 64)

    const uint4* Qp = (const uint4*)Qf;
    const uint4* Kp = (const uint4*)Kf + (size_t)b * 256 * 64;
    const uint2* Vq = (const uint2*)(Vf + (size_t)b * 1048576) + (size_t)hi * 1024 + low;
    int dt = wave * 2 + dsel;                // d-tile-of-16 (0..15)

    bf16x8 qa;
    if (isQK)
        qa = __builtin_bit_cast(bf16x8, Qp[(size_t)(b * 256 + g * 2 + t) * 64 + lane]);

    f32x16 acc = (f32x16)(0.f);              // O^T 32n x 32d tile
    float lacc = 0.f;
    const f32x4 zero = {0.f, 0.f, 0.f, 0.f};

    // ---- prologue: S^T(0) -> P(0), prefetch K(1), V(0) frags ----
    uint4 kv[2];
    f32x4 s[2];
    if (isQK) {
#pragma unroll
        for (int u = 0; u < 2; u++)
            kv[u] = Kp[(size_t)(h * 2 + u) * 64 + lane];
#pragma unroll
        for (int u = 0; u < 2; u++)
            s[u] = __builtin_amdgcn_mfma_f32_16x16x32_bf16(
                __builtin_bit_cast(bf16x8, kv[u]), qa, zero, 0, 0, 0);
#pragma unroll
        for (int u = 0; u < 2; u++)
            kv[u] = Kp[(size_t)(4 + h * 2 + u) * 64 + lane];
        unsigned char* Pw = &Pb[0][t][0];
#pragma unroll
        for (int u = 0; u < 2; u++) {
            float p0 = __expf(s[u][0] * SCALE_), p1 = __expf(s[u][1] * SCALE_);
            float p2 = __expf(s[u][2] * SCALE_), p3 = __expf(s[u][3] * SCALE_);
            lacc += p0 + p1 + p2 + p3;
            unsigned w = __builtin_amdgcn_cvt_pk_fp8_f32(p0, p1, 0, false);
            w = __builtin_amdgcn_cvt_pk_fp8_f32(p2, p3, w, true);
            *(unsigned*)(Pw + low * 80 + h * 32 + u * 16 + q * 4) = w;
        }
    }
    i32x8 vfc;
    {
        const uint2* Vs = Vq + (size_t)dt * 64;
        long* dqw = (long*)&vfc;
#pragma unroll
        for (int ss = 0; ss < 4; ss++)
            dqw[ss] = *(const long*)(Vs + ss * 16);
    }
    p_barrier();

    // ---- main loop over 64 m-slabs ----
    for (int i = 0; i < 64; i++) {
        int cur = i & 1, nxt = cur ^ 1;
        bool haveNext = (i + 1 < 64);

        i32x8 vfn;
        if (haveNext) {
            const uint2* Vs = Vq + (size_t)(i + 1) * 2048 + dt * 64;
            long* dqw = (long*)&vfn;
#pragma unroll
            for (int ss = 0; ss < 4; ss++)
                dqw[ss] = *(const long*)(Vs + ss * 16);
        }

        if (isQK && haveNext) {
#pragma unroll
            for (int u = 0; u < 2; u++)
                s[u] = __builtin_amdgcn_mfma_f32_16x16x32_bf16(
                    __builtin_bit_cast(bf16x8, kv[u]), qa, zero, 0, 0, 0);
            if (i + 2 < 64) {
#pragma unroll
                for (int u = 0; u < 2; u++)
                    kv[u] = Kp[(size_t)((i + 2) * 4 + h * 2 + u) * 64 + lane];
            }
        }

        // ---- PV(i): acc += V^T P^T (32x32x64, unit scales) ----
        {
            const unsigned char* pr = &Pb[cur][0][0] + dsel * 1280 + low * 80 + hi * 32;
            i32x8 pf;
            ((uint4*)&pf)[0] = *(const uint4*)pr;
            ((uint4*)&pf)[1] = *(const uint4*)(pr + 16);
            __builtin_amdgcn_s_setprio(1);
            acc = __builtin_amdgcn_mfma_scale_f32_32x32x64_f8f6f4(
                vfc, pf, acc, 0, 0, 0, 127, 0, 127);
            __builtin_amdgcn_s_setprio(0);
        }

        if (isQK && haveNext) {
            unsigned char* Pw = &Pb[nxt][t][0];
#pragma unroll
            for (int u = 0; u < 2; u++) {
                float p0 = __expf(s[u][0] * SCALE_), p1 = __expf(s[u][1] * SCALE_);
                float p2 = __expf(s[u][2] * SCALE_), p3 = __expf(s[u][3] * SCALE_);
                lacc += p0 + p1 + p2 + p3;
                unsigned w = __builtin_amdgcn_cvt_pk_fp8_f32(p0, p1, 0, false);
                w = __builtin_amdgcn_cvt_pk_fp8_f32(p2, p3, w, true);
                *(unsigned*)(Pw + low * 80 + h * 32 + u * 16 + q * 4) = w;
            }
        }
        if (haveNext) vfc = vfn;
        p_barrier();
    }

    // ---- l partials: reduce across quads, publish per (m-half, n) ----
    if (isQK) {
        lacc += __shfl_xor(lacc, 16, 64);
        lacc += __shfl_xor(lacc, 32, 64);
        if (lane < 16)
            l_sh[h][t * 16 + low] = lacc;
    }

    // ---- O^T -> bf16 LDS (row = n, col = d/2; stride 129 == 1 mod 32) ----
    // C layout: n = lane&31, d = wave*32 + (r&3) + 8*(r>>2) + 4*hi.
#pragma unroll
    for (int r = 0; r < 16; r += 2) {
        int col16 = wave * 16 + ((r >> 1) & 1) + 4 * (r >> 2) + 2 * hi;
        Ot[l31 * 129 + col16] = bfpk(acc[r], acc[r + 1]);
    }
    __syncthreads();

    // ---- out[b][d][n0+l31] = gamma * O/l + x ----
    {
        float gm = gamma[0];
        float rinv = gm / (l_sh[0][l31] + l_sh[1][l31]);
        int dh = lane >> 5;                 // d-half within wave's 32 d
        size_t nb = ((size_t)(b * 256 + wave * 32 + dh * 16)) * 4096
                    + (size_t)g * 32 + l31;
#pragma unroll 4
        for (int j = 0; j < 16; j++) {
            unsigned pk = Ot[l31 * 129 + wave * 16 + dh * 8 + (j >> 1)];
            unsigned bits = (j & 1) ? (pk & 0xffff0000u) : (pk << 16);
            float o = __uint_as_float(bits);
            size_t idx = nb + (size_t)j * 4096;
            out[idx] = o * rinv + x[idx];
        }
    }
}

// ---------------------------------------------------------------------------
extern "C" void kernel_launch(void* const* d_in, const int* in_sizes, int n_in,
                              void* d_out, int out_size, void* d_ws, size_t ws_size,
                              hipStream_t stream) {
    const float* x     = (const float*)d_in[0];
    const float* ctx   = (const float*)d_in[1];
    const float* Wq    = (const float*)d_in[2];
    const float* bq    = (const float*)d_in[3];
    const float* Wk    = (const float*)d_in[4];
    const float* bk    = (const float*)d_in[5];
    const float* Wv    = (const float*)d_in[6];
    const float* bv    = (const float*)d_in[7];
    const float* gamma = (const float*)d_in[8];
    float* out = (float*)d_out;

    // ws: Qf 1M | Kf 1M | Vf 4.2M | Wqf/Wkf 16K | Wvf 128K
    unsigned short* Qf = (unsigned short*)d_ws;
    unsigned short* Kf = Qf + (size_t)B_ * N_ * 32;
    unsigned char*  Vf = (unsigned char*)(Kf + (size_t)B_ * M_ * 32);
    uint4* Wqf = (uint4*)(Vf + (size_t)B_ * M_ * C_);
    uint4* Wkf = Wqf + 16 * 64;
    uint4* Wvf = Wkf + 16 * 64;

    prep<<<40, 256, 0, stream>>>(Wq, Wk, Wv, Wqf, Wkf, Wvf);
    fused_proj<<<512, 256, 0, stream>>>(x, ctx, Wqf, Wkf, Wvf, bq, bk, bv, Qf, Kf, Vf);
    attn<<<512, 512, 0, stream>>>(Qf, Kf, Vf, x, gamma, out);
}